// Round 1
// baseline (1394.631 us; speedup 1.0000x reference)
//
#include <hip/hip_runtime.h>

typedef __attribute__((ext_vector_type(8))) short short8;
typedef __attribute__((ext_vector_type(4))) float floatx4;

#define M_TOT 131072   // B*S = 64*2048
#define SEQ   2048
#define NB    8        // n-tiles (1024/128)

// ---------------------------------------------------------------------------
// Kernel 1: hvec[b,d] = b1[d] + sum_m hid[b,m] * W1[d, 1024+m]
// grid (64, 16), block 256 (4 waves); each wave computes 16 d's, lanes split m.
// ---------------------------------------------------------------------------
__global__ __launch_bounds__(256) void hvec_kernel(
    const float* __restrict__ hid, const float* __restrict__ W1,
    const float* __restrict__ b1, float* __restrict__ hvec)
{
  int b = blockIdx.x, g = blockIdx.y;
  int w = threadIdx.x >> 6, lane = threadIdx.x & 63;
  const float* hrow = hid + b * 1024;
  for (int i = 0; i < 16; ++i) {
    int d = g * 64 + w * 16 + i;
    const float* wrow = W1 + (size_t)d * 2048 + 1024;
    float sum = 0.f;
#pragma unroll
    for (int c = 0; c < 4; ++c) {
      int m = c * 256 + lane * 4;
      float4 wv = *(const float4*)(wrow + m);
      float4 hv = *(const float4*)(hrow + m);
      sum += wv.x * hv.x + wv.y * hv.y + wv.z * hv.z + wv.w * hv.w;
    }
#pragma unroll
    for (int msk = 1; msk < 64; msk <<= 1) sum += __shfl_xor(sum, msk);
    if (lane == 0) hvec[b * 1024 + d] = sum + b1[d];
  }
}

// ---------------------------------------------------------------------------
// Kernel 2: fused GEMM (enc @ W1e^T) + tanh + dot(W2) -> epart[nb][r]
// 128x128 tile, BK=32, 4 waves in 2x2, each wave 4x4 MFMA 16x16x32_bf16 tiles.
// fp32 -> bf16 (truncate) conversion at LDS staging time.
// grid (8 n-tiles, 1024 m-tiles), block 256.
// ---------------------------------------------------------------------------
__global__ __launch_bounds__(256) void fused_gemm_kernel(
    const float* __restrict__ enc, const float* __restrict__ W1,
    const float* __restrict__ W2, const float* __restrict__ hvec,
    float* __restrict__ epart)
{
  __shared__ __align__(16) unsigned short Ah[128 * 32];
  __shared__ __align__(16) unsigned short Bh[128 * 32];
  __shared__ float ep[2][128];

  const int tid = threadIdx.x;
  const int nb  = blockIdx.x;       // 0..7
  const int mb  = blockIdx.y;       // 0..1023
  const int r0  = mb * 128;
  const int n0  = nb * 128;
  const int bidx = r0 >> 11;        // batch index (128 | 2048, so uniform)
  const int w = tid >> 6, lane = tid & 63;
  const int wm = w >> 1, wn = w & 1;
  const int lrow = lane & 15, kq = lane >> 4;

  floatx4 acc[4][4];
#pragma unroll
  for (int i = 0; i < 4; ++i)
#pragma unroll
    for (int j = 0; j < 4; ++j)
      acc[i][j] = (floatx4){0.f, 0.f, 0.f, 0.f};

  // staging: float4 index f = tid + j*256; row = f>>3, col = (f&7)*4
  const int srow = tid >> 3;
  const int scol = (tid & 7) * 4;
  const float* aptr = enc + (size_t)(r0 + srow) * 1024 + scol;
  const float* bptr = W1  + (size_t)(n0 + srow) * 2048 + scol;

  for (int k0 = 0; k0 < 1024; k0 += 32) {
    float4 av[4], bv[4];
#pragma unroll
    for (int j = 0; j < 4; ++j) {
      av[j] = *(const float4*)(aptr + (size_t)(j * 32) * 1024 + k0);
      bv[j] = *(const float4*)(bptr + (size_t)(j * 32) * 2048 + k0);
    }
    __syncthreads();   // all waves done reading LDS from previous iter
#pragma unroll
    for (int j = 0; j < 4; ++j) {
      unsigned ax = __float_as_uint(av[j].x), ay = __float_as_uint(av[j].y);
      unsigned az = __float_as_uint(av[j].z), aw = __float_as_uint(av[j].w);
      // pack truncated-bf16 pairs: (hi16 of y)<<16 | (hi16 of x)  == v_perm_b32
      unsigned a01 = __builtin_amdgcn_perm(ay, ax, 0x07060302u);
      unsigned a23 = __builtin_amdgcn_perm(aw, az, 0x07060302u);
      *(uint2*)&Ah[(tid + j * 256) * 4] = make_uint2(a01, a23);

      unsigned bx = __float_as_uint(bv[j].x), by = __float_as_uint(bv[j].y);
      unsigned bz = __float_as_uint(bv[j].z), bw = __float_as_uint(bv[j].w);
      unsigned b01 = __builtin_amdgcn_perm(by, bx, 0x07060302u);
      unsigned b23 = __builtin_amdgcn_perm(bw, bz, 0x07060302u);
      *(uint2*)&Bh[(tid + j * 256) * 4] = make_uint2(b01, b23);
    }
    __syncthreads();   // writes visible

    short8 af[4], bfm[4];
#pragma unroll
    for (int t4 = 0; t4 < 4; ++t4) {
      af[t4]  = *(const short8*)&Ah[(wm * 64 + t4 * 16 + lrow) * 32 + kq * 8];
      bfm[t4] = *(const short8*)&Bh[(wn * 64 + t4 * 16 + lrow) * 32 + kq * 8];
    }
#pragma unroll
    for (int mt = 0; mt < 4; ++mt)
#pragma unroll
      for (int nt = 0; nt < 4; ++nt)
        acc[mt][nt] = __builtin_amdgcn_mfma_f32_16x16x32_bf16(
            af[mt], bfm[nt], acc[mt][nt], 0, 0, 0);
  }

  // epilogue: e-partial per row over this block's 128 d-columns
  float hv[4], w2v[4];
#pragma unroll
  for (int nt = 0; nt < 4; ++nt) {
    int n = n0 + wn * 64 + nt * 16 + lrow;
    hv[nt]  = hvec[bidx * 1024 + n];
    w2v[nt] = W2[n];
  }
#pragma unroll
  for (int mt = 0; mt < 4; ++mt) {
#pragma unroll
    for (int r = 0; r < 4; ++r) {
      float sum = 0.f;
#pragma unroll
      for (int nt = 0; nt < 4; ++nt) {
        float pre = acc[mt][nt][r] + hv[nt];
        float ex = __expf(2.f * pre);
        sum += (1.f - 2.f / (ex + 1.f)) * w2v[nt];   // tanh(pre), inf-safe
      }
      // reduce across the 16 lanes holding the same row (col = lane&15)
      sum += __shfl_xor(sum, 1);
      sum += __shfl_xor(sum, 2);
      sum += __shfl_xor(sum, 4);
      sum += __shfl_xor(sum, 8);
      if (lrow == 0) ep[wn][wm * 64 + mt * 16 + kq * 4 + r] = sum;
    }
  }
  __syncthreads();
  if (tid < 128)
    epart[(size_t)nb * M_TOT + r0 + tid] = ep[0][tid] + ep[1][tid];
}

// ---------------------------------------------------------------------------
// Kernel 3: e = sum of 8 partials; softmax over S per batch. grid 64, block 256.
// ---------------------------------------------------------------------------
__global__ __launch_bounds__(256) void softmax_kernel(
    const float* __restrict__ epart, float* __restrict__ alpha)
{
  int b = blockIdx.x, t = threadIdx.x;
  __shared__ float redmax[4], redsum[4];
  float ev[8];
  float lmax = -1e30f;
#pragma unroll
  for (int j = 0; j < 8; ++j) {
    int s = t + j * 256;
    float sum = 0.f;
#pragma unroll
    for (int p = 0; p < 8; ++p) sum += epart[(size_t)p * M_TOT + b * SEQ + s];
    ev[j] = sum;
    lmax = fmaxf(lmax, sum);
  }
#pragma unroll
  for (int msk = 1; msk < 64; msk <<= 1) lmax = fmaxf(lmax, __shfl_xor(lmax, msk));
  if ((t & 63) == 0) redmax[t >> 6] = lmax;
  __syncthreads();
  float bmax = fmaxf(fmaxf(redmax[0], redmax[1]), fmaxf(redmax[2], redmax[3]));
  float lsum = 0.f;
#pragma unroll
  for (int j = 0; j < 8; ++j) { ev[j] = __expf(ev[j] - bmax); lsum += ev[j]; }
#pragma unroll
  for (int msk = 1; msk < 64; msk <<= 1) lsum += __shfl_xor(lsum, msk);
  if ((t & 63) == 0) redsum[t >> 6] = lsum;
  __syncthreads();
  float inv = 1.f / (redsum[0] + redsum[1] + redsum[2] + redsum[3]);
#pragma unroll
  for (int j = 0; j < 8; ++j) alpha[b * SEQ + t + j * 256] = ev[j] * inv;
}

// ---------------------------------------------------------------------------
// Kernel 4: context[b,k] = sum_s alpha[b,s] * enc[b,s,k]  (fp32, HBM-bound)
// grid (1, 64, 16): z = s-chunk of 128; thread covers 4 k's; atomicAdd into out.
// ---------------------------------------------------------------------------
__global__ __launch_bounds__(256) void context_kernel(
    const float* __restrict__ enc, const float* __restrict__ alpha,
    float* __restrict__ out)
{
  int b = blockIdx.y, sq = blockIdx.z, t = threadIdx.x;
  int k4 = t * 4;
  const float* ep = enc + ((size_t)b * SEQ + sq * 128) * 1024 + k4;
  const float* ap = alpha + b * SEQ + sq * 128;
  float ax = 0.f, ay = 0.f, az = 0.f, aw = 0.f;
#pragma unroll 4
  for (int s = 0; s < 128; ++s) {
    float a = ap[s];
    float4 v = *(const float4*)(ep + (size_t)s * 1024);
    ax += a * v.x; ay += a * v.y; az += a * v.z; aw += a * v.w;
  }
  float* o = out + b * 1024 + k4;
  atomicAdd(o + 0, ax);
  atomicAdd(o + 1, ay);
  atomicAdd(o + 2, az);
  atomicAdd(o + 3, aw);
}

// ---------------------------------------------------------------------------
extern "C" void kernel_launch(void* const* d_in, const int* in_sizes, int n_in,
                              void* d_out, int out_size, void* d_ws, size_t ws_size,
                              hipStream_t stream) {
  const float* hid = (const float*)d_in[0];   // (64, 1024)
  const float* enc = (const float*)d_in[1];   // (64, 2048, 1024)
  const float* W1  = (const float*)d_in[2];   // (1024, 2048)
  const float* b1  = (const float*)d_in[3];   // (1024,)
  const float* W2  = (const float*)d_in[4];   // (1, 1024)
  float* out = (float*)d_out;                 // (64, 1024)

  // workspace layout (~5 MiB): epart[8][M_TOT], alpha[M_TOT], hvec[64*1024]
  float* epart = (float*)d_ws;
  float* alpha = epart + (size_t)NB * M_TOT;
  float* hvec  = alpha + M_TOT;

  hipMemsetAsync(d_out, 0, (size_t)out_size * sizeof(float), stream);
  hvec_kernel<<<dim3(64, 16), 256, 0, stream>>>(hid, W1, b1, hvec);
  fused_gemm_kernel<<<dim3(NB, 1024), 256, 0, stream>>>(enc, W1, W2, hvec, epart);
  softmax_kernel<<<64, 256, 0, stream>>>(epart, alpha);
  context_kernel<<<dim3(1, 64, 16), 256, 0, stream>>>(enc, alpha, out);
}

// Round 2
// 1270.378 us; speedup vs baseline: 1.0978x; 1.0978x over previous
//
#include <hip/hip_runtime.h>

typedef __attribute__((ext_vector_type(8))) short short8;
typedef __attribute__((ext_vector_type(4))) float floatx4;

#define M_TOT 131072   // B*S = 64*2048
#define SEQ   2048
#define NB    8        // n-tiles (1024/128)

__device__ __forceinline__ unsigned bf16rne(float x) {
  unsigned u = __float_as_uint(x);
  return (u + 0x7FFFu + ((u >> 16) & 1u)) >> 16;
}

#define GLOAD_LDS16(g, l) __builtin_amdgcn_global_load_lds( \
    (const __attribute__((address_space(1))) unsigned int*)(g), \
    (__attribute__((address_space(3))) unsigned int*)(l), 16, 0, 0)

// ---------------------------------------------------------------------------
// Convert enc fp32 -> bf16 (RNE). 134217728 elems, 8/thread.
// ---------------------------------------------------------------------------
__global__ __launch_bounds__(256) void convert_enc_kernel(
    const float* __restrict__ in, unsigned int* __restrict__ out)
{
  size_t i = ((size_t)blockIdx.x * 256 + threadIdx.x) * 8;
  float4 a = *(const float4*)(in + i);
  float4 b = *(const float4*)(in + i + 4);
  uint4 o;
  o.x = bf16rne(a.x) | (bf16rne(a.y) << 16);
  o.y = bf16rne(a.z) | (bf16rne(a.w) << 16);
  o.z = bf16rne(b.x) | (bf16rne(b.y) << 16);
  o.w = bf16rne(b.z) | (bf16rne(b.w) << 16);
  *(uint4*)(out + i / 2) = o;
}

// ---------------------------------------------------------------------------
// Convert W1e (first 1024 cols of W1's 2048-wide rows) fp32 -> bf16.
// grid 1024 (one block per d-row), 128 threads x 8 elems.
// ---------------------------------------------------------------------------
__global__ __launch_bounds__(128) void convert_w1e_kernel(
    const float* __restrict__ W1, unsigned int* __restrict__ out)
{
  int d = blockIdx.x;
  int k = threadIdx.x * 8;
  const float* p = W1 + (size_t)d * 2048 + k;
  float4 a = *(const float4*)p;
  float4 b = *(const float4*)(p + 4);
  uint4 o;
  o.x = bf16rne(a.x) | (bf16rne(a.y) << 16);
  o.y = bf16rne(a.z) | (bf16rne(a.w) << 16);
  o.z = bf16rne(b.x) | (bf16rne(b.y) << 16);
  o.w = bf16rne(b.z) | (bf16rne(b.w) << 16);
  *(uint4*)(out + ((size_t)d * 1024 + k) / 2) = o;
}

// ---------------------------------------------------------------------------
// Kernel 1: hvec[b,d] = b1[d] + sum_m hid[b,m] * W1[d, 1024+m]
// ---------------------------------------------------------------------------
__global__ __launch_bounds__(256) void hvec_kernel(
    const float* __restrict__ hid, const float* __restrict__ W1,
    const float* __restrict__ b1, float* __restrict__ hvec)
{
  int b = blockIdx.x, g = blockIdx.y;
  int w = threadIdx.x >> 6, lane = threadIdx.x & 63;
  const float* hrow = hid + b * 1024;
  for (int i = 0; i < 16; ++i) {
    int d = g * 64 + w * 16 + i;
    const float* wrow = W1 + (size_t)d * 2048 + 1024;
    float sum = 0.f;
#pragma unroll
    for (int c = 0; c < 4; ++c) {
      int m = c * 256 + lane * 4;
      float4 wv = *(const float4*)(wrow + m);
      float4 hv = *(const float4*)(hrow + m);
      sum += wv.x * hv.x + wv.y * hv.y + wv.z * hv.z + wv.w * hv.w;
    }
#pragma unroll
    for (int msk = 1; msk < 64; msk <<= 1) sum += __shfl_xor(sum, msk);
    if (lane == 0) hvec[b * 1024 + d] = sum + b1[d];
  }
}

// ---------------------------------------------------------------------------
// Kernel 2 (primary): m97-style bf16 GEMM + tanh + W2-dot -> epart.
// A = encB (M_TOT x 1024, bf16 row-major), B = W1eB (1024 x 1024 bf16).
// 128x128 tile, BK=32, global_load_lds width-16 staging, 4 waves 2x2,
// each wave 4x4 tiles of 16x16x32 MFMA.
// ---------------------------------------------------------------------------
__global__ __launch_bounds__(256) void gemm_bf16_kernel(
    const unsigned short* __restrict__ A, const unsigned short* __restrict__ B,
    const float* __restrict__ W2, const float* __restrict__ hvec,
    float* __restrict__ epart)
{
  __shared__ __align__(16) unsigned short Ah[128 * 32];
  __shared__ __align__(16) unsigned short Bh[128 * 32];
  __shared__ float ep[2][128];

  const int tid = threadIdx.x;
  const int nb = blockIdx.x;       // 0..7
  const int mb = blockIdx.y;       // 0..1023
  const int r0 = mb * 128, n0 = nb * 128;
  const int bidx = r0 >> 11;
  const int w = tid >> 6, lane = tid & 63;
  const int wm = w >> 1, wn = w & 1;
  const int lrow = lane & 15, kq = lane >> 4;

  floatx4 acc[4][4];
#pragma unroll
  for (int i = 0; i < 4; ++i)
#pragma unroll
    for (int j = 0; j < 4; ++j)
      acc[i][j] = (floatx4){0.f, 0.f, 0.f, 0.f};

  const unsigned short* aBase = A + (size_t)r0 * 1024;
  const unsigned short* bBase = B + (size_t)n0 * 1024;

  for (int k0 = 0; k0 < 1024; k0 += 32) {
    __syncthreads();   // previous iter's ds_reads done before overwrite
#pragma unroll
    for (int j = 0; j < 2; ++j) {
      int c = tid + j * 256;            // 16B-chunk id, 0..511
      int row = c >> 2, kc = c & 3;
      const unsigned short* ag = aBase + (size_t)row * 1024 + k0 + kc * 8;
      const unsigned short* bg = bBase + (size_t)row * 1024 + k0 + kc * 8;
      int ldsbase = (w * 64 + j * 256) * 8;   // elements (wave-uniform)
      GLOAD_LDS16(ag, &Ah[ldsbase]);
      GLOAD_LDS16(bg, &Bh[ldsbase]);
    }
    __syncthreads();   // vmcnt(0) drain: staged data visible

    short8 af[4], bfm[4];
#pragma unroll
    for (int t4 = 0; t4 < 4; ++t4) {
      af[t4]  = *(const short8*)&Ah[(wm * 64 + t4 * 16 + lrow) * 32 + kq * 8];
      bfm[t4] = *(const short8*)&Bh[(wn * 64 + t4 * 16 + lrow) * 32 + kq * 8];
    }
#pragma unroll
    for (int mt = 0; mt < 4; ++mt)
#pragma unroll
      for (int nt = 0; nt < 4; ++nt)
        acc[mt][nt] = __builtin_amdgcn_mfma_f32_16x16x32_bf16(
            af[mt], bfm[nt], acc[mt][nt], 0, 0, 0);
  }

  float hv[4], w2v[4];
#pragma unroll
  for (int nt = 0; nt < 4; ++nt) {
    int n = n0 + wn * 64 + nt * 16 + lrow;
    hv[nt]  = hvec[bidx * 1024 + n];
    w2v[nt] = W2[n];
  }
#pragma unroll
  for (int mt = 0; mt < 4; ++mt) {
#pragma unroll
    for (int r = 0; r < 4; ++r) {
      float sum = 0.f;
#pragma unroll
      for (int nt = 0; nt < 4; ++nt) {
        float pre = acc[mt][nt][r] + hv[nt];
        float ex = __expf(2.f * pre);
        sum += (1.f - 2.f / (ex + 1.f)) * w2v[nt];
      }
      sum += __shfl_xor(sum, 1);
      sum += __shfl_xor(sum, 2);
      sum += __shfl_xor(sum, 4);
      sum += __shfl_xor(sum, 8);
      if (lrow == 0) ep[wn][wm * 64 + mt * 16 + kq * 4 + r] = sum;
    }
  }
  __syncthreads();
  if (tid < 128)
    epart[(size_t)nb * M_TOT + r0 + tid] = ep[0][tid] + ep[1][tid];
}

// ---------------------------------------------------------------------------
// Kernel 2 (fallback, no-ws path): round-1 fused GEMM with in-loop convert.
// ---------------------------------------------------------------------------
__global__ __launch_bounds__(256) void fused_gemm_kernel(
    const float* __restrict__ enc, const float* __restrict__ W1,
    const float* __restrict__ W2, const float* __restrict__ hvec,
    float* __restrict__ epart)
{
  __shared__ __align__(16) unsigned short Ah[128 * 32];
  __shared__ __align__(16) unsigned short Bh[128 * 32];
  __shared__ float ep[2][128];

  const int tid = threadIdx.x;
  const int nb = blockIdx.x, mb = blockIdx.y;
  const int r0 = mb * 128, n0 = nb * 128;
  const int bidx = r0 >> 11;
  const int w = tid >> 6, lane = tid & 63;
  const int wm = w >> 1, wn = w & 1;
  const int lrow = lane & 15, kq = lane >> 4;

  floatx4 acc[4][4];
#pragma unroll
  for (int i = 0; i < 4; ++i)
#pragma unroll
    for (int j = 0; j < 4; ++j)
      acc[i][j] = (floatx4){0.f, 0.f, 0.f, 0.f};

  const int srow = tid >> 3;
  const int scol = (tid & 7) * 4;
  const float* aptr = enc + (size_t)(r0 + srow) * 1024 + scol;
  const float* bptr = W1  + (size_t)(n0 + srow) * 2048 + scol;

  for (int k0 = 0; k0 < 1024; k0 += 32) {
    float4 av[4], bv[4];
#pragma unroll
    for (int j = 0; j < 4; ++j) {
      av[j] = *(const float4*)(aptr + (size_t)(j * 32) * 1024 + k0);
      bv[j] = *(const float4*)(bptr + (size_t)(j * 32) * 2048 + k0);
    }
    __syncthreads();
#pragma unroll
    for (int j = 0; j < 4; ++j) {
      unsigned ax = __float_as_uint(av[j].x), ay = __float_as_uint(av[j].y);
      unsigned az = __float_as_uint(av[j].z), aw = __float_as_uint(av[j].w);
      unsigned a01 = __builtin_amdgcn_perm(ay, ax, 0x07060302u);
      unsigned a23 = __builtin_amdgcn_perm(aw, az, 0x07060302u);
      *(uint2*)&Ah[(tid + j * 256) * 4] = make_uint2(a01, a23);
      unsigned bx = __float_as_uint(bv[j].x), by = __float_as_uint(bv[j].y);
      unsigned bz = __float_as_uint(bv[j].z), bw = __float_as_uint(bv[j].w);
      unsigned b01 = __builtin_amdgcn_perm(by, bx, 0x07060302u);
      unsigned b23 = __builtin_amdgcn_perm(bw, bz, 0x07060302u);
      *(uint2*)&Bh[(tid + j * 256) * 4] = make_uint2(b01, b23);
    }
    __syncthreads();

    short8 af[4], bfm[4];
#pragma unroll
    for (int t4 = 0; t4 < 4; ++t4) {
      af[t4]  = *(const short8*)&Ah[(wm * 64 + t4 * 16 + lrow) * 32 + kq * 8];
      bfm[t4] = *(const short8*)&Bh[(wn * 64 + t4 * 16 + lrow) * 32 + kq * 8];
    }
#pragma unroll
    for (int mt = 0; mt < 4; ++mt)
#pragma unroll
      for (int nt = 0; nt < 4; ++nt)
        acc[mt][nt] = __builtin_amdgcn_mfma_f32_16x16x32_bf16(
            af[mt], bfm[nt], acc[mt][nt], 0, 0, 0);
  }

  float hv[4], w2v[4];
#pragma unroll
  for (int nt = 0; nt < 4; ++nt) {
    int n = n0 + wn * 64 + nt * 16 + lrow;
    hv[nt]  = hvec[bidx * 1024 + n];
    w2v[nt] = W2[n];
  }
#pragma unroll
  for (int mt = 0; mt < 4; ++mt) {
#pragma unroll
    for (int r = 0; r < 4; ++r) {
      float sum = 0.f;
#pragma unroll
      for (int nt = 0; nt < 4; ++nt) {
        float pre = acc[mt][nt][r] + hv[nt];
        float ex = __expf(2.f * pre);
        sum += (1.f - 2.f / (ex + 1.f)) * w2v[nt];
      }
      sum += __shfl_xor(sum, 1);
      sum += __shfl_xor(sum, 2);
      sum += __shfl_xor(sum, 4);
      sum += __shfl_xor(sum, 8);
      if (lrow == 0) ep[wn][wm * 64 + mt * 16 + kq * 4 + r] = sum;
    }
  }
  __syncthreads();
  if (tid < 128)
    epart[(size_t)nb * M_TOT + r0 + tid] = ep[0][tid] + ep[1][tid];
}

// ---------------------------------------------------------------------------
// Kernel 3: softmax over S per batch.
// ---------------------------------------------------------------------------
__global__ __launch_bounds__(256) void softmax_kernel(
    const float* __restrict__ epart, float* __restrict__ alpha)
{
  int b = blockIdx.x, t = threadIdx.x;
  __shared__ float redmax[4], redsum[4];
  float ev[8];
  float lmax = -1e30f;
#pragma unroll
  for (int j = 0; j < 8; ++j) {
    int s = t + j * 256;
    float sum = 0.f;
#pragma unroll
    for (int p = 0; p < 8; ++p) sum += epart[(size_t)p * M_TOT + b * SEQ + s];
    ev[j] = sum;
    lmax = fmaxf(lmax, sum);
  }
#pragma unroll
  for (int msk = 1; msk < 64; msk <<= 1) lmax = fmaxf(lmax, __shfl_xor(lmax, msk));
  if ((t & 63) == 0) redmax[t >> 6] = lmax;
  __syncthreads();
  float bmax = fmaxf(fmaxf(redmax[0], redmax[1]), fmaxf(redmax[2], redmax[3]));
  float lsum = 0.f;
#pragma unroll
  for (int j = 0; j < 8; ++j) { ev[j] = __expf(ev[j] - bmax); lsum += ev[j]; }
#pragma unroll
  for (int msk = 1; msk < 64; msk <<= 1) lsum += __shfl_xor(lsum, msk);
  if ((t & 63) == 0) redsum[t >> 6] = lsum;
  __syncthreads();
  float inv = 1.f / (redsum[0] + redsum[1] + redsum[2] + redsum[3]);
#pragma unroll
  for (int j = 0; j < 8; ++j) alpha[b * SEQ + t + j * 256] = ev[j] * inv;
}

// ---------------------------------------------------------------------------
// Kernel 4 (primary): context from bf16 enc. grid (64, 32), block 128.
// Each block: 64 s-rows x 1024 k. Thread covers 8 k's (16B loads).
// ---------------------------------------------------------------------------
__global__ __launch_bounds__(128) void context_bf16_kernel(
    const unsigned int* __restrict__ encB, const float* __restrict__ alpha,
    float* __restrict__ out)
{
  int b = blockIdx.x, sc = blockIdx.y, t = threadIdx.x;
  int k8 = t * 8;
  const unsigned int* ep = encB + (((size_t)b * SEQ + sc * 64) * 1024 + k8) / 2;
  const float* ap = alpha + b * SEQ + sc * 64;
  float a0 = 0.f, a1 = 0.f, a2 = 0.f, a3 = 0.f, a4 = 0.f, a5 = 0.f, a6 = 0.f, a7 = 0.f;
#pragma unroll 4
  for (int s = 0; s < 64; ++s) {
    float a = ap[s];
    uint4 v = *(const uint4*)(ep + (size_t)s * 512);
    a0 += a * __uint_as_float(v.x << 16);
    a1 += a * __uint_as_float(v.x & 0xFFFF0000u);
    a2 += a * __uint_as_float(v.y << 16);
    a3 += a * __uint_as_float(v.y & 0xFFFF0000u);
    a4 += a * __uint_as_float(v.z << 16);
    a5 += a * __uint_as_float(v.z & 0xFFFF0000u);
    a6 += a * __uint_as_float(v.w << 16);
    a7 += a * __uint_as_float(v.w & 0xFFFF0000u);
  }
  float* o = out + b * 1024 + k8;
  atomicAdd(o + 0, a0); atomicAdd(o + 1, a1);
  atomicAdd(o + 2, a2); atomicAdd(o + 3, a3);
  atomicAdd(o + 4, a4); atomicAdd(o + 5, a5);
  atomicAdd(o + 6, a6); atomicAdd(o + 7, a7);
}

// ---------------------------------------------------------------------------
// Kernel 4 (fallback): fp32 context.
// ---------------------------------------------------------------------------
__global__ __launch_bounds__(256) void context_kernel(
    const float* __restrict__ enc, const float* __restrict__ alpha,
    float* __restrict__ out)
{
  int b = blockIdx.y, sq = blockIdx.z, t = threadIdx.x;
  int k4 = t * 4;
  const float* ep = enc + ((size_t)b * SEQ + sq * 128) * 1024 + k4;
  const float* ap = alpha + b * SEQ + sq * 128;
  float ax = 0.f, ay = 0.f, az = 0.f, aw = 0.f;
#pragma unroll 4
  for (int s = 0; s < 128; ++s) {
    float a = ap[s];
    float4 v = *(const float4*)(ep + (size_t)s * 1024);
    ax += a * v.x; ay += a * v.y; az += a * v.z; aw += a * v.w;
  }
  float* o = out + b * 1024 + k4;
  atomicAdd(o + 0, ax);
  atomicAdd(o + 1, ay);
  atomicAdd(o + 2, az);
  atomicAdd(o + 3, aw);
}

// ---------------------------------------------------------------------------
extern "C" void kernel_launch(void* const* d_in, const int* in_sizes, int n_in,
                              void* d_out, int out_size, void* d_ws, size_t ws_size,
                              hipStream_t stream) {
  const float* hid = (const float*)d_in[0];
  const float* enc = (const float*)d_in[1];
  const float* W1  = (const float*)d_in[2];
  const float* b1  = (const float*)d_in[3];
  const float* W2  = (const float*)d_in[4];
  float* out = (float*)d_out;

  float* epart = (float*)d_ws;                       // NB * M_TOT
  float* alpha = epart + (size_t)NB * M_TOT;         // M_TOT
  float* hvec  = alpha + M_TOT;                      // 64*1024
  size_t small_bytes = ((size_t)NB * M_TOT + M_TOT + 64 * 1024) * 4;
  size_t encB_off = ((small_bytes + 255) / 256) * 256;
  size_t need = encB_off + (size_t)M_TOT * 1024 * 2 + (size_t)1024 * 1024 * 2;

  hipMemsetAsync(d_out, 0, (size_t)out_size * sizeof(float), stream);
  hvec_kernel<<<dim3(64, 16), 256, 0, stream>>>(hid, W1, b1, hvec);

  if (ws_size >= need) {
    unsigned short* encB = (unsigned short*)((char*)d_ws + encB_off);
    unsigned short* W1eB = encB + (size_t)M_TOT * 1024;
    convert_enc_kernel<<<65536, 256, 0, stream>>>(enc, (unsigned int*)encB);
    convert_w1e_kernel<<<1024, 128, 0, stream>>>(W1, (unsigned int*)W1eB);
    gemm_bf16_kernel<<<dim3(NB, 1024), 256, 0, stream>>>(encB, W1eB, W2, hvec, epart);
    softmax_kernel<<<64, 256, 0, stream>>>(epart, alpha);
    context_bf16_kernel<<<dim3(64, 32), 128, 0, stream>>>((unsigned int*)encB, alpha, out);
  } else {
    fused_gemm_kernel<<<dim3(NB, 1024), 256, 0, stream>>>(enc, W1, W2, hvec, epart);
    softmax_kernel<<<64, 256, 0, stream>>>(epart, alpha);
    context_kernel<<<dim3(1, 64, 16), 256, 0, stream>>>(enc, alpha, out);
  }
}

// Round 3
// 1159.832 us; speedup vs baseline: 1.2024x; 1.0953x over previous
//
#include <hip/hip_runtime.h>

typedef __attribute__((ext_vector_type(8))) short short8;
typedef __attribute__((ext_vector_type(4))) float floatx4;

#define M_TOT 131072   // B*S = 64*2048
#define SEQ   2048
#define NB    8        // n-tiles (1024/128)

__device__ __forceinline__ unsigned bf16rne(float x) {
  unsigned u = __float_as_uint(x);
  return (u + 0x7FFFu + ((u >> 16) & 1u)) >> 16;
}

#define GLOAD_LDS16(g, l) __builtin_amdgcn_global_load_lds( \
    (const __attribute__((address_space(1))) unsigned int*)(g), \
    (__attribute__((address_space(3))) unsigned int*)(l), 16, 0, 0)

// ---------------------------------------------------------------------------
// Convert enc fp32 -> bf16 (RNE). 134217728 elems, 8/thread.
// ---------------------------------------------------------------------------
__global__ __launch_bounds__(256) void convert_enc_kernel(
    const float* __restrict__ in, unsigned int* __restrict__ out)
{
  size_t i = ((size_t)blockIdx.x * 256 + threadIdx.x) * 8;
  float4 a = *(const float4*)(in + i);
  float4 b = *(const float4*)(in + i + 4);
  uint4 o;
  o.x = bf16rne(a.x) | (bf16rne(a.y) << 16);
  o.y = bf16rne(a.z) | (bf16rne(a.w) << 16);
  o.z = bf16rne(b.x) | (bf16rne(b.y) << 16);
  o.w = bf16rne(b.z) | (bf16rne(b.w) << 16);
  *(uint4*)(out + i / 2) = o;
}

// ---------------------------------------------------------------------------
// Convert W1e (first 1024 cols of W1's 2048-wide rows) fp32 -> bf16.
// ---------------------------------------------------------------------------
__global__ __launch_bounds__(128) void convert_w1e_kernel(
    const float* __restrict__ W1, unsigned int* __restrict__ out)
{
  int d = blockIdx.x;
  int k = threadIdx.x * 8;
  const float* p = W1 + (size_t)d * 2048 + k;
  float4 a = *(const float4*)p;
  float4 b = *(const float4*)(p + 4);
  uint4 o;
  o.x = bf16rne(a.x) | (bf16rne(a.y) << 16);
  o.y = bf16rne(a.z) | (bf16rne(a.w) << 16);
  o.z = bf16rne(b.x) | (bf16rne(b.y) << 16);
  o.w = bf16rne(b.z) | (bf16rne(b.w) << 16);
  *(uint4*)(out + ((size_t)d * 1024 + k) / 2) = o;
}

// ---------------------------------------------------------------------------
// Kernel 1: hvec[b,d] = b1[d] + sum_m hid[b,m] * W1[d, 1024+m]
// ---------------------------------------------------------------------------
__global__ __launch_bounds__(256) void hvec_kernel(
    const float* __restrict__ hid, const float* __restrict__ W1,
    const float* __restrict__ b1, float* __restrict__ hvec)
{
  int b = blockIdx.x, g = blockIdx.y;
  int w = threadIdx.x >> 6, lane = threadIdx.x & 63;
  const float* hrow = hid + b * 1024;
  for (int i = 0; i < 16; ++i) {
    int d = g * 64 + w * 16 + i;
    const float* wrow = W1 + (size_t)d * 2048 + 1024;
    float sum = 0.f;
#pragma unroll
    for (int c = 0; c < 4; ++c) {
      int m = c * 256 + lane * 4;
      float4 wv = *(const float4*)(wrow + m);
      float4 hv = *(const float4*)(hrow + m);
      sum += wv.x * hv.x + wv.y * hv.y + wv.z * hv.z + wv.w * hv.w;
    }
#pragma unroll
    for (int msk = 1; msk < 64; msk <<= 1) sum += __shfl_xor(sum, msk);
    if (lane == 0) hvec[b * 1024 + d] = sum + b1[d];
  }
}

// ---------------------------------------------------------------------------
// Kernel 2 (primary): m97-style bf16 GEMM + tanh + W2-dot -> epart.
// XCD-aware work remap: linear id lid -> xcd = lid&7 (round-robin dispatch);
// XCD x processes mb in [x*128, x*128+128), nb fastest -> the 8 blocks
// sharing an A tile are consecutive on the SAME XCD -> A served by its L2.
// ---------------------------------------------------------------------------
__global__ __launch_bounds__(256) void gemm_bf16_kernel(
    const unsigned short* __restrict__ A, const unsigned short* __restrict__ B,
    const float* __restrict__ W2, const float* __restrict__ hvec,
    float* __restrict__ epart)
{
  __shared__ __align__(16) unsigned short Ah[128 * 32];
  __shared__ __align__(16) unsigned short Bh[128 * 32];
  __shared__ float ep[2][128];

  const int tid = threadIdx.x;
  const int lid = blockIdx.x + blockIdx.y * 8;   // 0..8191
  const int xcd = lid & 7;
  const int q   = lid >> 3;                      // 0..1023
  const int mb  = (xcd << 7) + (q >> 3);         // 0..1023
  const int nb  = q & 7;                         // 0..7
  const int r0 = mb * 128, n0 = nb * 128;
  const int bidx = r0 >> 11;
  const int w = tid >> 6, lane = tid & 63;
  const int wm = w >> 1, wn = w & 1;
  const int lrow = lane & 15, kq = lane >> 4;

  floatx4 acc[4][4];
#pragma unroll
  for (int i = 0; i < 4; ++i)
#pragma unroll
    for (int j = 0; j < 4; ++j)
      acc[i][j] = (floatx4){0.f, 0.f, 0.f, 0.f};

  const unsigned short* aBase = A + (size_t)r0 * 1024;
  const unsigned short* bBase = B + (size_t)n0 * 1024;

  for (int k0 = 0; k0 < 1024; k0 += 32) {
    __syncthreads();
#pragma unroll
    for (int j = 0; j < 2; ++j) {
      int c = tid + j * 256;            // 16B-chunk id, 0..511
      int row = c >> 2, kc = c & 3;
      const unsigned short* ag = aBase + (size_t)row * 1024 + k0 + kc * 8;
      const unsigned short* bg = bBase + (size_t)row * 1024 + k0 + kc * 8;
      int ldsbase = (w * 64 + j * 256) * 8;   // elements (wave-uniform)
      GLOAD_LDS16(ag, &Ah[ldsbase]);
      GLOAD_LDS16(bg, &Bh[ldsbase]);
    }
    __syncthreads();

    short8 af[4], bfm[4];
#pragma unroll
    for (int t4 = 0; t4 < 4; ++t4) {
      af[t4]  = *(const short8*)&Ah[(wm * 64 + t4 * 16 + lrow) * 32 + kq * 8];
      bfm[t4] = *(const short8*)&Bh[(wn * 64 + t4 * 16 + lrow) * 32 + kq * 8];
    }
#pragma unroll
    for (int mt = 0; mt < 4; ++mt)
#pragma unroll
      for (int nt = 0; nt < 4; ++nt)
        acc[mt][nt] = __builtin_amdgcn_mfma_f32_16x16x32_bf16(
            af[mt], bfm[nt], acc[mt][nt], 0, 0, 0);
  }

  float hv[4], w2v[4];
#pragma unroll
  for (int nt = 0; nt < 4; ++nt) {
    int n = n0 + wn * 64 + nt * 16 + lrow;
    hv[nt]  = hvec[bidx * 1024 + n];
    w2v[nt] = W2[n];
  }
#pragma unroll
  for (int mt = 0; mt < 4; ++mt) {
#pragma unroll
    for (int r = 0; r < 4; ++r) {
      float sum = 0.f;
#pragma unroll
      for (int nt = 0; nt < 4; ++nt) {
        float pre = acc[mt][nt][r] + hv[nt];
        float ex = __expf(2.f * pre);
        sum += (1.f - 2.f / (ex + 1.f)) * w2v[nt];
      }
      sum += __shfl_xor(sum, 1);
      sum += __shfl_xor(sum, 2);
      sum += __shfl_xor(sum, 4);
      sum += __shfl_xor(sum, 8);
      if (lrow == 0) ep[wn][wm * 64 + mt * 16 + kq * 4 + r] = sum;
    }
  }
  __syncthreads();
  if (tid < 128)
    epart[(size_t)nb * M_TOT + r0 + tid] = ep[0][tid] + ep[1][tid];
}

// ---------------------------------------------------------------------------
// Kernel 2 (fallback, no-ws path): fused GEMM with in-loop convert.
// ---------------------------------------------------------------------------
__global__ __launch_bounds__(256) void fused_gemm_kernel(
    const float* __restrict__ enc, const float* __restrict__ W1,
    const float* __restrict__ W2, const float* __restrict__ hvec,
    float* __restrict__ epart)
{
  __shared__ __align__(16) unsigned short Ah[128 * 32];
  __shared__ __align__(16) unsigned short Bh[128 * 32];
  __shared__ float ep[2][128];

  const int tid = threadIdx.x;
  const int nb = blockIdx.x, mb = blockIdx.y;
  const int r0 = mb * 128, n0 = nb * 128;
  const int bidx = r0 >> 11;
  const int w = tid >> 6, lane = tid & 63;
  const int wm = w >> 1, wn = w & 1;
  const int lrow = lane & 15, kq = lane >> 4;

  floatx4 acc[4][4];
#pragma unroll
  for (int i = 0; i < 4; ++i)
#pragma unroll
    for (int j = 0; j < 4; ++j)
      acc[i][j] = (floatx4){0.f, 0.f, 0.f, 0.f};

  const int srow = tid >> 3;
  const int scol = (tid & 7) * 4;
  const float* aptr = enc + (size_t)(r0 + srow) * 1024 + scol;
  const float* bptr = W1  + (size_t)(n0 + srow) * 2048 + scol;

  for (int k0 = 0; k0 < 1024; k0 += 32) {
    float4 av[4], bv[4];
#pragma unroll
    for (int j = 0; j < 4; ++j) {
      av[j] = *(const float4*)(aptr + (size_t)(j * 32) * 1024 + k0);
      bv[j] = *(const float4*)(bptr + (size_t)(j * 32) * 2048 + k0);
    }
    __syncthreads();
#pragma unroll
    for (int j = 0; j < 4; ++j) {
      unsigned ax = __float_as_uint(av[j].x), ay = __float_as_uint(av[j].y);
      unsigned az = __float_as_uint(av[j].z), aw = __float_as_uint(av[j].w);
      unsigned a01 = __builtin_amdgcn_perm(ay, ax, 0x07060302u);
      unsigned a23 = __builtin_amdgcn_perm(aw, az, 0x07060302u);
      *(uint2*)&Ah[(tid + j * 256) * 4] = make_uint2(a01, a23);
      unsigned bx = __float_as_uint(bv[j].x), by = __float_as_uint(bv[j].y);
      unsigned bz = __float_as_uint(bv[j].z), bw = __float_as_uint(bv[j].w);
      unsigned b01 = __builtin_amdgcn_perm(by, bx, 0x07060302u);
      unsigned b23 = __builtin_amdgcn_perm(bw, bz, 0x07060302u);
      *(uint2*)&Bh[(tid + j * 256) * 4] = make_uint2(b01, b23);
    }
    __syncthreads();

    short8 af[4], bfm[4];
#pragma unroll
    for (int t4 = 0; t4 < 4; ++t4) {
      af[t4]  = *(const short8*)&Ah[(wm * 64 + t4 * 16 + lrow) * 32 + kq * 8];
      bfm[t4] = *(const short8*)&Bh[(wn * 64 + t4 * 16 + lrow) * 32 + kq * 8];
    }
#pragma unroll
    for (int mt = 0; mt < 4; ++mt)
#pragma unroll
      for (int nt = 0; nt < 4; ++nt)
        acc[mt][nt] = __builtin_amdgcn_mfma_f32_16x16x32_bf16(
            af[mt], bfm[nt], acc[mt][nt], 0, 0, 0);
  }

  float hv[4], w2v[4];
#pragma unroll
  for (int nt = 0; nt < 4; ++nt) {
    int n = n0 + wn * 64 + nt * 16 + lrow;
    hv[nt]  = hvec[bidx * 1024 + n];
    w2v[nt] = W2[n];
  }
#pragma unroll
  for (int mt = 0; mt < 4; ++mt) {
#pragma unroll
    for (int r = 0; r < 4; ++r) {
      float sum = 0.f;
#pragma unroll
      for (int nt = 0; nt < 4; ++nt) {
        float pre = acc[mt][nt][r] + hv[nt];
        float ex = __expf(2.f * pre);
        sum += (1.f - 2.f / (ex + 1.f)) * w2v[nt];
      }
      sum += __shfl_xor(sum, 1);
      sum += __shfl_xor(sum, 2);
      sum += __shfl_xor(sum, 4);
      sum += __shfl_xor(sum, 8);
      if (lrow == 0) ep[wn][wm * 64 + mt * 16 + kq * 4 + r] = sum;
    }
  }
  __syncthreads();
  if (tid < 128)
    epart[(size_t)nb * M_TOT + r0 + tid] = ep[0][tid] + ep[1][tid];
}

// ---------------------------------------------------------------------------
// Kernel 3: softmax over S per batch.
// ---------------------------------------------------------------------------
__global__ __launch_bounds__(256) void softmax_kernel(
    const float* __restrict__ epart, float* __restrict__ alpha)
{
  int b = blockIdx.x, t = threadIdx.x;
  __shared__ float redmax[4], redsum[4];
  float ev[8];
  float lmax = -1e30f;
#pragma unroll
  for (int j = 0; j < 8; ++j) {
    int s = t + j * 256;
    float sum = 0.f;
#pragma unroll
    for (int p = 0; p < 8; ++p) sum += epart[(size_t)p * M_TOT + b * SEQ + s];
    ev[j] = sum;
    lmax = fmaxf(lmax, sum);
  }
#pragma unroll
  for (int msk = 1; msk < 64; msk <<= 1) lmax = fmaxf(lmax, __shfl_xor(lmax, msk));
  if ((t & 63) == 0) redmax[t >> 6] = lmax;
  __syncthreads();
  float bmax = fmaxf(fmaxf(redmax[0], redmax[1]), fmaxf(redmax[2], redmax[3]));
  float lsum = 0.f;
#pragma unroll
  for (int j = 0; j < 8; ++j) { ev[j] = __expf(ev[j] - bmax); lsum += ev[j]; }
#pragma unroll
  for (int msk = 1; msk < 64; msk <<= 1) lsum += __shfl_xor(lsum, msk);
  if ((t & 63) == 0) redsum[t >> 6] = lsum;
  __syncthreads();
  float inv = 1.f / (redsum[0] + redsum[1] + redsum[2] + redsum[3]);
#pragma unroll
  for (int j = 0; j < 8; ++j) alpha[b * SEQ + t + j * 256] = ev[j] * inv;
}

// ---------------------------------------------------------------------------
// Kernel 4 (primary): context, atomic-free. grid (64, 8), block 256.
// Block = (batch b, 128-wide k-chunk). 8 s-strips of 256; thread covers 4 k's.
// LDS reduce across strips; single coalesced write. No memset needed.
// ---------------------------------------------------------------------------
__global__ __launch_bounds__(256) void context_bf16_kernel(
    const unsigned int* __restrict__ encB, const float* __restrict__ alpha,
    float* __restrict__ out)
{
  __shared__ float red[8][128];
  int b = blockIdx.x, kc = blockIdx.y, t = threadIdx.x;
  int kl = (t & 31) * 4;              // k-local 0..124
  int strip = t >> 5;                 // 0..7
  const unsigned int* ep = encB +
      (((size_t)b * SEQ + strip * 256) * 1024 + kc * 128 + kl) / 2;
  const float* ap = alpha + b * SEQ + strip * 256;
  float a0 = 0.f, a1 = 0.f, a2 = 0.f, a3 = 0.f;
#pragma unroll 4
  for (int s = 0; s < 256; ++s) {
    float a = ap[s];
    uint2 v = *(const uint2*)(ep + (size_t)s * 512);
    a0 += a * __uint_as_float(v.x << 16);
    a1 += a * __uint_as_float(v.x & 0xFFFF0000u);
    a2 += a * __uint_as_float(v.y << 16);
    a3 += a * __uint_as_float(v.y & 0xFFFF0000u);
  }
  red[strip][kl + 0] = a0;
  red[strip][kl + 1] = a1;
  red[strip][kl + 2] = a2;
  red[strip][kl + 3] = a3;
  __syncthreads();
  if (t < 128) {
    float s = 0.f;
#pragma unroll
    for (int j = 0; j < 8; ++j) s += red[j][t];
    out[b * 1024 + kc * 128 + t] = s;
  }
}

// ---------------------------------------------------------------------------
// Kernel 4 (fallback): fp32 context with atomics.
// ---------------------------------------------------------------------------
__global__ __launch_bounds__(256) void context_kernel(
    const float* __restrict__ enc, const float* __restrict__ alpha,
    float* __restrict__ out)
{
  int b = blockIdx.y, sq = blockIdx.z, t = threadIdx.x;
  int k4 = t * 4;
  const float* ep = enc + ((size_t)b * SEQ + sq * 128) * 1024 + k4;
  const float* ap = alpha + b * SEQ + sq * 128;
  float ax = 0.f, ay = 0.f, az = 0.f, aw = 0.f;
#pragma unroll 4
  for (int s = 0; s < 128; ++s) {
    float a = ap[s];
    float4 v = *(const float4*)(ep + (size_t)s * 1024);
    ax += a * v.x; ay += a * v.y; az += a * v.z; aw += a * v.w;
  }
  float* o = out + b * 1024 + k4;
  atomicAdd(o + 0, ax);
  atomicAdd(o + 1, ay);
  atomicAdd(o + 2, az);
  atomicAdd(o + 3, aw);
}

// ---------------------------------------------------------------------------
extern "C" void kernel_launch(void* const* d_in, const int* in_sizes, int n_in,
                              void* d_out, int out_size, void* d_ws, size_t ws_size,
                              hipStream_t stream) {
  const float* hid = (const float*)d_in[0];
  const float* enc = (const float*)d_in[1];
  const float* W1  = (const float*)d_in[2];
  const float* b1  = (const float*)d_in[3];
  const float* W2  = (const float*)d_in[4];
  float* out = (float*)d_out;

  float* epart = (float*)d_ws;                       // NB * M_TOT
  float* alpha = epart + (size_t)NB * M_TOT;         // M_TOT
  float* hvec  = alpha + M_TOT;                      // 64*1024
  size_t small_bytes = ((size_t)NB * M_TOT + M_TOT + 64 * 1024) * 4;
  size_t encB_off = ((small_bytes + 255) / 256) * 256;
  size_t need = encB_off + (size_t)M_TOT * 1024 * 2 + (size_t)1024 * 1024 * 2;

  hvec_kernel<<<dim3(64, 16), 256, 0, stream>>>(hid, W1, b1, hvec);

  if (ws_size >= need) {
    unsigned short* encB = (unsigned short*)((char*)d_ws + encB_off);
    unsigned short* W1eB = encB + (size_t)M_TOT * 1024;
    convert_enc_kernel<<<65536, 256, 0, stream>>>(enc, (unsigned int*)encB);
    convert_w1e_kernel<<<1024, 128, 0, stream>>>(W1, (unsigned int*)W1eB);
    gemm_bf16_kernel<<<dim3(NB, 1024), 256, 0, stream>>>(encB, W1eB, W2, hvec, epart);
    softmax_kernel<<<64, 256, 0, stream>>>(epart, alpha);
    context_bf16_kernel<<<dim3(64, 8), 256, 0, stream>>>((unsigned int*)encB, alpha, out);
  } else {
    hipMemsetAsync(d_out, 0, (size_t)out_size * sizeof(float), stream);
    fused_gemm_kernel<<<dim3(NB, 1024), 256, 0, stream>>>(enc, W1, W2, hvec, epart);
    softmax_kernel<<<64, 256, 0, stream>>>(epart, alpha);
    context_kernel<<<dim3(1, 64, 16), 256, 0, stream>>>(enc, alpha, out);
  }
}